// Round 23
// baseline (160.773 us; speedup 1.0000x reference)
//
#include <hip/hip_runtime.h>
#include <hip/hip_bf16.h>

#define TOK 8192
#define CDIM 768
#define NH 12
#define HD 64
#define QKV_N 2304
// 0.125 * log2(e): QK^T scale folded into Q, softmax runs in exp2 domain
#define QSCALE 0.18033688011f
// deferred-max reference (exp2 domain): P = 2^(S' - MREF) <= 1 for S' <= MREF
#define MREF 10.0f

typedef __attribute__((ext_vector_type(8))) short bf16x8;
typedef __attribute__((ext_vector_type(4))) float f32x4;
typedef unsigned short ushort_t;

__device__ __forceinline__ ushort_t f2bf(float f) {
  unsigned u = __float_as_uint(f);
  u += 0x7fffu + ((u >> 16) & 1u);
  return (ushort_t)(u >> 16);
}

__device__ __forceinline__ float bf2f(ushort_t b) {
  return __uint_as_float(((unsigned)b) << 16);
}

__device__ __forceinline__ f32x4 mfma16(bf16x8 a, bf16x8 b, f32x4 c) {
  return __builtin_amdgcn_mfma_f32_16x16x32_bf16(a, b, c, 0, 0, 0);
}

// XOR swizzle for 8-chunk (64-col) bf16 LDS rows
__device__ __forceinline__ int swz(int r) { return (r ^ (r >> 3)) & 7; }

__device__ __forceinline__ void gload16(const void* g, void* l) {
  __builtin_amdgcn_global_load_lds(
      (const __attribute__((address_space(1))) unsigned int*)g,
      (__attribute__((address_space(3))) unsigned int*)l, 16, 0, 0);
}

// ------- Fused prep: LN (0..8191) + wtrans (8192..10495) + pos->bf16 ---------
// pos conversion VECTORIZED (r19's regression was scalar 2B stores):
// each thread: 2x float4 load -> 4 packed dwords -> 1 uint4 store.
__global__ __launch_bounds__(256) void prep_kernel(
    const float* __restrict__ x, const float* __restrict__ gamma,
    const float* __restrict__ beta, ushort_t* __restrict__ xn,
    const float* __restrict__ Wq, const float* __restrict__ Wk,
    const float* __restrict__ Wv, const float* __restrict__ Wo,
    ushort_t* __restrict__ wt,
    const float* __restrict__ pos, ushort_t* __restrict__ posb) {
  __shared__ float red[8];
  __shared__ float tile[32][33];
  const int bid = blockIdx.x;
  const int tid = threadIdx.x;

  if (bid < TOK) {
    // ---------------- LayerNorm: 1 block per token ----------------
    const float* row = x + (size_t)bid * CDIM;
    float v[3];
    float s = 0.f, s2 = 0.f;
#pragma unroll
    for (int i = 0; i < 3; i++) {
      v[i] = row[tid + 256 * i];
      s += v[i];
      s2 += v[i] * v[i];
    }
#pragma unroll
    for (int off = 32; off; off >>= 1) {
      s += __shfl_xor(s, off);
      s2 += __shfl_xor(s2, off);
    }
    int wid = tid >> 6, lane = tid & 63;
    if (lane == 0) { red[wid] = s; red[wid + 4] = s2; }
    __syncthreads();
    s = red[0] + red[1] + red[2] + red[3];
    s2 = red[4] + red[5] + red[6] + red[7];
    float mu = s * (1.f / CDIM);
    float var = s2 * (1.f / CDIM) - mu * mu;
    float rstd = rsqrtf(var + 1e-5f);
    ushort_t* orow = xn + (size_t)bid * CDIM;
#pragma unroll
    for (int i = 0; i < 3; i++) {
      int c = tid + 256 * i;
      orow[c] = f2bf((v[i] - mu) * rstd * gamma[c] + beta[c]);
    }
  } else if (bid < TOK + 2304) {
    // ------- weight transpose: wt[z][n][k] = W_z[k][n], 32x32 tiles -------
    int zi = bid - TOK;
    int z = zi / 576;
    int rem = zi % 576;
    int trr = rem / 24, tcc = rem % 24;
    const float* W = (z == 0) ? Wq : (z == 1) ? Wk : (z == 2) ? Wv : Wo;
    int tx = tid & 31, ty = tid >> 5;
#pragma unroll
    for (int j = 0; j < 4; j++) {
      int k = trr * 32 + ty + j * 8;
      tile[ty + j * 8][tx] = W[(size_t)k * CDIM + tcc * 32 + tx];
    }
    __syncthreads();
    ushort_t* o = wt + (size_t)z * CDIM * CDIM;
#pragma unroll
    for (int j = 0; j < 4; j++) {
      int n = tcc * 32 + ty + j * 8;
      o[(size_t)n * CDIM + trr * 32 + tx] = f2bf(tile[tx][ty + j * 8]);
    }
  } else {
    // ---- pos fp32 -> bf16, vectorized: 2048 elems/block, 8/thread ----
    size_t base = (size_t)(bid - TOK - 2304) * 2048 + (size_t)tid * 8;
    float p[8];
    *reinterpret_cast<float4*>(&p[0]) = *reinterpret_cast<const float4*>(&pos[base]);
    *reinterpret_cast<float4*>(&p[4]) = *reinterpret_cast<const float4*>(&pos[base + 4]);
    uint4 d;
    unsigned* dw = reinterpret_cast<unsigned*>(&d);
#pragma unroll
    for (int j = 0; j < 4; j++)
      dw[j] = (unsigned)f2bf(p[2 * j]) | ((unsigned)f2bf(p[2 * j + 1]) << 16);
    *reinterpret_cast<uint4*>(&posb[base]) = d;
  }
}

// -------- QKV GEMM: 3 sequential N=768 panels + LDS-bounce epilogue ----------
// Q-panel epilogue reads posb (bf16, r19-measured +2.5us). Bounce fenced by
// __syncthreads (r22 race fix).
__global__ __launch_bounds__(256) void gemm0_kernel(
    const ushort_t* __restrict__ A, const ushort_t* __restrict__ wt,
    const float* __restrict__ bq, const float* __restrict__ bk,
    const float* __restrict__ bv, const ushort_t* __restrict__ posb,
    ushort_t* __restrict__ outp) {
  __shared__ __align__(16) ushort_t smem[32768];  // 64KB: staging + bounce
  ushort_t* lds_a0 = smem;                 // [2][128*64] A buffers
  ushort_t* lds_b0 = smem + 16384;         // [2][128*64] B buffers
  const int NB = 6;
  const int z = blockIdx.x / 384;          // QKV panel (runs ~sequentially)
  const int lin2 = blockIdx.x % 384;
  // within-panel XCD-chunked swizzle (384 % 8 == 0)
  int nl = (lin2 & 7) * 48 + (lin2 >> 3);
  const int bn = nl % NB, bm = nl / NB;
  const ushort_t* Bt = wt + (size_t)z * CDIM * CDIM;

  const int tid = threadIdx.x;
  const int lane = tid & 63, wid = tid >> 6;
  const int wr = wid >> 1, wc = wid & 1;
  const int l16 = lane & 15, lg = lane >> 4;
  f32x4 acc[4][4] = {};

  int aoff[2][4], boff[2][4];
#pragma unroll
  for (int kk = 0; kk < 2; kk++) {
#pragma unroll
    for (int mi = 0; mi < 4; mi++) {
      int r = wr * 64 + mi * 16 + l16;
      aoff[kk][mi] = r * 64 + (((kk * 4 + lg) ^ swz(r)) & 7) * 8;
    }
#pragma unroll
    for (int ni = 0; ni < 4; ni++) {
      int r = wc * 64 + ni * 16 + l16;
      boff[kk][ni] = r * 64 + (((kk * 4 + lg) ^ swz(r)) & 7) * 8;
    }
  }

  auto stage = [&](int buf, int k0) {
#pragma unroll
    for (int i = 0; i < 4; i++) {
      int slot = i * 256 + tid;
      int row = slot >> 3, j = slot & 7;
      int c8 = ((j ^ swz(row)) & 7) * 8;  // pre-swizzled source column
      gload16(&A[(size_t)(bm * 128 + row) * CDIM + k0 + c8],
              &lds_a0[buf * 8192 + slot * 8]);
      gload16(&Bt[(size_t)(bn * 128 + row) * CDIM + k0 + c8],
              &lds_b0[buf * 8192 + slot * 8]);
    }
  };

  stage(0, 0);
  asm volatile("s_waitcnt vmcnt(0)" ::: "memory");
  __builtin_amdgcn_s_barrier();
  __builtin_amdgcn_sched_barrier(0);

  int cur = 0;
#pragma unroll 2
  for (int t = 0; t < 12; t++) {
    if (t < 11) stage(cur ^ 1, (t + 1) * 64);  // issue next tile early
#pragma unroll
    for (int kk = 0; kk < 2; kk++) {
      bf16x8 af[4], bfr[4];
#pragma unroll
      for (int mi = 0; mi < 4; mi++)
        af[mi] = *reinterpret_cast<const bf16x8*>(&lds_a0[cur * 8192 + aoff[kk][mi]]);
#pragma unroll
      for (int ni = 0; ni < 4; ni++)
        bfr[ni] = *reinterpret_cast<const bf16x8*>(&lds_b0[cur * 8192 + boff[kk][ni]]);
      __builtin_amdgcn_s_setprio(1);
#pragma unroll
      for (int mi = 0; mi < 4; mi++)
#pragma unroll
        for (int ni = 0; ni < 4; ni++)
          acc[mi][ni] = mfma16(af[mi], bfr[ni], acc[mi][ni]);
      __builtin_amdgcn_s_setprio(0);
    }
    asm volatile("s_waitcnt vmcnt(0) lgkmcnt(0)" ::: "memory");
    __builtin_amdgcn_s_barrier();
    __builtin_amdgcn_sched_barrier(0);
    cur ^= 1;
  }

  // ---- epilogue: full LDS fence, then bias -> bf16 bounce -> coalesced ----
  __syncthreads();  // REAL memory fence: no ds_write may precede it
  const int BST = 136;  // row stride in ushorts; 136%8==0 keeps 16B alignment
#pragma unroll
  for (int mi = 0; mi < 4; mi++)
#pragma unroll
    for (int ni = 0; ni < 4; ni++)
#pragma unroll
      for (int r = 0; r < 4; r++) {
        int lrow = wr * 64 + mi * 16 + 4 * lg + r;
        int lcol = wc * 64 + ni * 16 + l16;
        int gcol = bn * 128 + lcol;
        float v = acc[mi][ni][r];
        if (z == 0) {
          int grow = bm * 128 + lrow;
          v = (v + bq[gcol] + bf2f(posb[(size_t)grow * CDIM + gcol])) * QSCALE;
        } else if (z == 1) {
          v += bk[gcol];
        } else {
          v += bv[gcol];
        }
        smem[lrow * BST + lcol] = f2bf(v);
      }
  __syncthreads();
  {
    int lrow = tid >> 1, half = (tid & 1) * 64;
    int grow = bm * 128 + lrow;
    ushort_t* dst = &outp[(size_t)grow * QKV_N + z * CDIM + bn * 128 + half];
    const ushort_t* src = &smem[lrow * BST + half];
#pragma unroll
    for (int j = 0; j < 8; j++)
      *reinterpret_cast<uint4*>(&dst[j * 8]) =
          *reinterpret_cast<const uint4*>(&src[j * 8]);
  }
}

// -------- out-proj GEMM (r10-proven 128^2 BK=64 overlapped dbuf) -------------
__global__ __launch_bounds__(256) void gemm1_kernel(
    const ushort_t* __restrict__ A, const ushort_t* __restrict__ Bt,
    const float* __restrict__ b0, const float* __restrict__ extra,
    float* __restrict__ outp) {
  __shared__ __align__(16) ushort_t lds_a[2][128 * 64];
  __shared__ __align__(16) ushort_t lds_b[2][128 * 64];
  const int NB = 6;
  int lin = blockIdx.y * NB + blockIdx.x;
  int nl = (lin & 7) * (NB * 8) + (lin >> 3);
  const int bn = nl % NB, bm = nl / NB;

  const int tid = threadIdx.x;
  const int lane = tid & 63, wid = tid >> 6;
  const int wr = wid >> 1, wc = wid & 1;
  const int l16 = lane & 15, lg = lane >> 4;
  f32x4 acc[4][4] = {};

  int aoff[2][4], boff[2][4];
#pragma unroll
  for (int kk = 0; kk < 2; kk++) {
#pragma unroll
    for (int mi = 0; mi < 4; mi++) {
      int r = wr * 64 + mi * 16 + l16;
      aoff[kk][mi] = r * 64 + (((kk * 4 + lg) ^ swz(r)) & 7) * 8;
    }
#pragma unroll
    for (int ni = 0; ni < 4; ni++) {
      int r = wc * 64 + ni * 16 + l16;
      boff[kk][ni] = r * 64 + (((kk * 4 + lg) ^ swz(r)) & 7) * 8;
    }
  }

  auto stage = [&](int buf, int k0) {
#pragma unroll
    for (int i = 0; i < 4; i++) {
      int slot = i * 256 + tid;
      int row = slot >> 3, j = slot & 7;
      int c8 = ((j ^ swz(row)) & 7) * 8;
      gload16(&A[(size_t)(bm * 128 + row) * CDIM + k0 + c8], &lds_a[buf][slot * 8]);
      gload16(&Bt[(size_t)(bn * 128 + row) * CDIM + k0 + c8], &lds_b[buf][slot * 8]);
    }
  };

  stage(0, 0);
  asm volatile("s_waitcnt vmcnt(0)" ::: "memory");
  __builtin_amdgcn_s_barrier();
  __builtin_amdgcn_sched_barrier(0);

  int cur = 0;
#pragma unroll 2
  for (int t = 0; t < 12; t++) {
    if (t < 11) stage(cur ^ 1, (t + 1) * 64);
#pragma unroll
    for (int kk = 0; kk < 2; kk++) {
      bf16x8 af[4], bfr[4];
#pragma unroll
      for (int mi = 0; mi < 4; mi++)
        af[mi] = *reinterpret_cast<const bf16x8*>(&lds_a[cur][aoff[kk][mi]]);
#pragma unroll
      for (int ni = 0; ni < 4; ni++)
        bfr[ni] = *reinterpret_cast<const bf16x8*>(&lds_b[cur][boff[kk][ni]]);
      __builtin_amdgcn_s_setprio(1);
#pragma unroll
      for (int mi = 0; mi < 4; mi++)
#pragma unroll
        for (int ni = 0; ni < 4; ni++)
          acc[mi][ni] = mfma16(af[mi], bfr[ni], acc[mi][ni]);
      __builtin_amdgcn_s_setprio(0);
    }
    asm volatile("s_waitcnt vmcnt(0) lgkmcnt(0)" ::: "memory");
    __builtin_amdgcn_s_barrier();
    __builtin_amdgcn_sched_barrier(0);
    cur ^= 1;
  }

#pragma unroll
  for (int mi = 0; mi < 4; mi++)
#pragma unroll
    for (int ni = 0; ni < 4; ni++)
#pragma unroll
      for (int r = 0; r < 4; r++) {
        int grow = bm * 128 + wr * 64 + mi * 16 + 4 * lg + r;
        int gcol = bn * 128 + wc * 64 + ni * 16 + l16;
        outp[(size_t)grow * CDIM + gcol] =
            acc[mi][ni][r] + b0[gcol] + extra[(size_t)grow * CDIM + gcol];
      }
}

// -------- Flash attention v9: K-in-LDS, QBLK=128 (r18 version, no pos) -------
__global__ __launch_bounds__(256, 3) void attn_kernel(const ushort_t* __restrict__ QKV,
                                                      ushort_t* __restrict__ O) {
  const int b = blockIdx.x, h = blockIdx.y, qt = blockIdx.z;

  const int tid = threadIdx.x, lane = tid & 63, w = tid >> 6;
  const int l16 = lane & 15, lg = lane >> 4;
  const int tb = b * 1024 + qt * 128;
  const int co_q = h * HD, co_k = CDIM + h * HD, co_v = 2 * CDIM + h * HD;

  __shared__ __align__(16) ushort_t k_lds[2][64 * 64];
  __shared__ __align__(16) ushort_t vt_lds[2][64 * 64];
  __shared__ __align__(16) ushort_t p_lds[128 * 64];

  bf16x8 qf[2][2];
#pragma unroll
  for (int mi = 0; mi < 2; mi++)
#pragma unroll
    for (int ds = 0; ds < 2; ds++)
      qf[mi][ds] = *reinterpret_cast<const bf16x8*>(
          &QKV[(size_t)(tb + w * 32 + mi * 16 + l16) * QKV_N + co_q + ds * 32 + 8 * lg]);

  float m_sm[2] = {MREF, MREF};
  float l_sm[2] = {0.f, 0.f};
  float m_acc[2][4];
#pragma unroll
  for (int mi = 0; mi < 2; mi++)
#pragma unroll
    for (int r = 0; r < 4; r++) m_acc[mi][r] = MREF;
  f32x4 oacc[2][4] = {};

  int kfoff[2][4];
#pragma unroll
  for (int ds = 0; ds < 2; ds++)
#pragma unroll
    for (int ni = 0; ni < 4; ni++) {
      int rr = ni * 16 + l16;
      kfoff[ds][ni] = rr * 64 + (((ds * 4 + lg) ^ swz(rr)) & 7) * 8;
    }
  int poff[2][4], paoff[2][2];
#pragma unroll
  for (int mi = 0; mi < 2; mi++) {
    int myq = w * 32 + mi * 16 + l16;
    int sq = swz(myq);
#pragma unroll
    for (int ni = 0; ni < 4; ni++)
      poff[mi][ni] = myq * 64 + (lg & 1) * 4 + (((ni * 2 + (lg >> 1)) ^ sq) & 7) * 8;
#pragma unroll
    for (int ks = 0; ks < 2; ks++)
      paoff[mi][ks] = myq * 64 + (((ks * 4 + lg) ^ sq) & 7) * 8;
  }
  int vboff[2][4];
#pragma unroll
  for (int ks = 0; ks < 2; ks++)
#pragma unroll
    for (int ni = 0; ni < 4; ni++) {
      int d = ni * 16 + l16;
      vboff[ks][ni] = d * 64 + (((ks * 4 + lg) ^ swz(d)) & 7) * 8;
    }

  auto stage_k = [&](int buf, int kt) {
    const int kv0 = kt * 64;
#pragma unroll
    for (int i = 0; i < 2; i++) {
      int slot = i * 256 + tid;
      int r = slot >> 3, j = slot & 7;
      int c = ((j ^ swz(r)) & 7) * 8;
      gload16(&QKV[(size_t)(b * 1024 + kv0 + r) * QKV_N + co_k + c],
              &k_lds[buf][slot * 8]);
    }
  };

  const int kv0 = (tid >> 3) * 2, d0 = (tid & 7) * 8;
  const int sV = ((kv0 >> 3) ^ (d0 >> 3)) & 7;
  int voff[8];
#pragma unroll
  for (int u = 0; u < 8; u++)
    voff[u] = (d0 + u) * 64 + ((sV ^ u) & 7) * 8 + (kv0 & 7);
  const ushort_t* vsrc = QKV + (size_t)(b * 1024 + kv0) * QKV_N + co_v + d0;

  uint4 vr0, vr1;
  auto load_v = [&](int kt) {
    vr0 = *reinterpret_cast<const uint4*>(vsrc + (size_t)kt * 64 * QKV_N);
    vr1 = *reinterpret_cast<const uint4*>(vsrc + (size_t)kt * 64 * QKV_N + QKV_N);
  };
  auto write_v = [&](int buf) {
    const unsigned* w0 = reinterpret_cast<const unsigned*>(&vr0);
    const unsigned* w1 = reinterpret_cast<const unsigned*>(&vr1);
#pragma unroll
    for (int u = 0; u < 8; u++) {
      unsigned a = w0[u >> 1], c = w1[u >> 1];
      unsigned val = (u & 1) ? ((a >> 16) | (c & 0xffff0000u))
                             : ((a & 0xffffu) | (c << 16));
      *reinterpret_cast<unsigned*>(&vt_lds[buf][voff[u]]) = val;
    }
  };

  stage_k(0, 0);
  load_v(0);
  write_v(0);
  asm volatile("s_waitcnt vmcnt(0) lgkmcnt(0)" ::: "memory");
  __builtin_amdgcn_s_barrier();
  __builtin_amdgcn_sched_barrier(0);

  for (int kt = 0; kt < 16; kt++) {
    const int cur = kt & 1, nxt = cur ^ 1;
    if (kt < 15) { stage_k(nxt, kt + 1); load_v(kt + 1); }

    bf16x8 kf[2][4];
#pragma unroll
    for (int ds = 0; ds < 2; ds++)
#pragma unroll
      for (int ni = 0; ni < 4; ni++)
        kf[ds][ni] = *reinterpret_cast<const bf16x8*>(&k_lds[cur][kfoff[ds][ni]]);

#pragma unroll
    for (int mi = 0; mi < 2; mi++) {
      f32x4 st[4] = {};
      __builtin_amdgcn_s_setprio(1);
#pragma unroll
      for (int ds = 0; ds < 2; ds++)
#pragma unroll
        for (int ni = 0; ni < 4; ni++)
          st[ni] = mfma16(kf[ds][ni], qf[mi][ds], st[ni]);
      __builtin_amdgcn_s_setprio(0);

      float t0 = fmaxf(fmaxf(st[0][0], st[0][1]), fmaxf(st[0][2], st[0][3]));
      float t1 = fmaxf(fmaxf(st[1][0], st[1][1]), fmaxf(st[1][2], st[1][3]));
      float t2 = fmaxf(fmaxf(st[2][0], st[2][1]), fmaxf(st[2][2], st[2][3]));
      float t3 = fmaxf(fmaxf(st[3][0], st[3][1]), fmaxf(st[3][2], st[3][3]));
      float tm = fmaxf(fmaxf(t0, t1), fmaxf(t2, t3));

      if (__any(tm > m_sm[mi])) {
        float rm = fmaxf(tm, __shfl_xor(tm, 16));
        rm = fmaxf(rm, __shfl_xor(rm, 32));
        float mnew = fmaxf(m_sm[mi], rm);
        l_sm[mi] *= exp2f(m_sm[mi] - mnew);
        m_sm[mi] = mnew;
#pragma unroll
        for (int r = 0; r < 4; r++) {
          float mn = __shfl(mnew, 4 * lg + r);
          float corr = exp2f(m_acc[mi][r] - mn);
          m_acc[mi][r] = mn;
#pragma unroll
          for (int ni = 0; ni < 4; ni++) oacc[mi][ni][r] *= corr;
        }
      }

      float ps[4];
#pragma unroll
      for (int ni = 0; ni < 4; ni++) {
        float e0 = exp2f(st[ni][0] - m_sm[mi]);
        float e1 = exp2f(st[ni][1] - m_sm[mi]);
        float e2 = exp2f(st[ni][2] - m_sm[mi]);
        float e3 = exp2f(st[ni][3] - m_sm[mi]);
        st[ni][0] = e0; st[ni][1] = e1; st[ni][2] = e2; st[ni][3] = e3;
        ps[ni] = (e0 + e1) + (e2 + e3);
      }
      l_sm[mi] += (ps[0] + ps[1]) + (ps[2] + ps[3]);

#pragma unroll
      for (int ni = 0; ni < 4; ni++) {
        unsigned p01, p23;
        asm("v_cvt_pk_bf16_f32 %0, %1, %2" : "=v"(p01) : "v"(st[ni][0]), "v"(st[ni][1]));
        asm("v_cvt_pk_bf16_f32 %0, %1, %2" : "=v"(p23) : "v"(st[ni][2]), "v"(st[ni][3]));
        uint2 pk; pk.x = p01; pk.y = p23;
        *reinterpret_cast<uint2*>(&p_lds[poff[mi][ni]]) = pk;
      }
    }

#pragma unroll
    for (int ks = 0; ks < 2; ks++) {
      bf16x8 pa0 = *reinterpret_cast<const bf16x8*>(&p_lds[paoff[0][ks]]);
      bf16x8 pa1 = *reinterpret_cast<const bf16x8*>(&p_lds[paoff[1][ks]]);
      bf16x8 vb[4];
#pragma unroll
      for (int ni = 0; ni < 4; ni++)
        vb[ni] = *reinterpret_cast<const bf16x8*>(&vt_lds[cur][vboff[ks][ni]]);
      __builtin_amdgcn_s_setprio(1);
#pragma unroll
      for (int ni = 0; ni < 4; ni++) {
        oacc[0][ni] = mfma16(pa0, vb[ni], oacc[0][ni]);
        oacc[1][ni] = mfma16(pa1, vb[ni], oacc[1][ni]);
      }
      __builtin_amdgcn_s_setprio(0);
    }

    if (kt < 15) write_v(nxt);
    asm volatile("s_waitcnt vmcnt(0) lgkmcnt(0)" ::: "memory");
    __builtin_amdgcn_s_barrier();
    __builtin_amdgcn_sched_barrier(0);
  }

#pragma unroll
  for (int mi = 0; mi < 2; mi++) {
    float l = l_sm[mi];
    l += __shfl_xor(l, 16);
    l += __shfl_xor(l, 32);
#pragma unroll
    for (int r = 0; r < 4; r++) {
      float lr = __shfl(l, 4 * lg + r);
      float inv = 1.f / lr;
      int grow = tb + w * 32 + mi * 16 + 4 * lg + r;
#pragma unroll
      for (int ni = 0; ni < 4; ni++) {
        int gcol = h * HD + ni * 16 + l16;
        O[(size_t)grow * CDIM + gcol] = f2bf(oacc[mi][ni][r] * inv);
      }
    }
  }
}

extern "C" void kernel_launch(void* const* d_in, const int* in_sizes, int n_in,
                              void* d_out, int out_size, void* d_ws, size_t ws_size,
                              hipStream_t stream) {
  const float* x     = (const float*)d_in[0];
  const float* pos   = (const float*)d_in[1];
  const float* gamma = (const float*)d_in[2];
  const float* beta  = (const float*)d_in[3];
  const float* Wq    = (const float*)d_in[4];
  const float* bq    = (const float*)d_in[5];
  const float* Wk    = (const float*)d_in[6];
  const float* bk    = (const float*)d_in[7];
  const float* Wv    = (const float*)d_in[8];
  const float* bv    = (const float*)d_in[9];
  const float* Wo    = (const float*)d_in[10];
  const float* bo    = (const float*)d_in[11];
  float* out = (float*)d_out;

  ushort_t* xn   = (ushort_t*)d_ws;                    // 8192*768
  ushort_t* wt   = xn + (size_t)TOK * CDIM;            // 3072*768 (q,k,v,o transposed)
  ushort_t* qkv  = wt + (size_t)3072 * CDIM;           // 8192*2304
  ushort_t* aout = qkv + (size_t)TOK * QKV_N;          // 8192*768
  ushort_t* posb = aout + (size_t)TOK * CDIM;          // 8192*768 (pos as bf16)

  prep_kernel<<<TOK + 2304 + 3072, 256, 0, stream>>>(x, gamma, beta, xn,
                                                     Wq, Wk, Wv, Wo, wt,
                                                     pos, posb);
  gemm0_kernel<<<1152, 256, 0, stream>>>(xn, wt, bq, bk, bv, posb, qkv);
  attn_kernel<<<dim3(8, NH, 8), 256, 0, stream>>>(qkv, aout);
  gemm1_kernel<<<dim3(6, 64), 256, 0, stream>>>(aout, wt + (size_t)QKV_N * CDIM,
                                                bo, x, out);
}

// Round 24
// 155.367 us; speedup vs baseline: 1.0348x; 1.0348x over previous
//
#include <hip/hip_runtime.h>
#include <hip/hip_bf16.h>

#define TOK 8192
#define CDIM 768
#define NH 12
#define HD 64
#define QKV_N 2304
// 0.125 * log2(e): QK^T scale folded into Q, softmax runs in exp2 domain
#define QSCALE 0.18033688011f
// deferred-max reference (exp2 domain): P = 2^(S' - MREF) <= 1 for S' <= MREF
#define MREF 10.0f

typedef __attribute__((ext_vector_type(8))) short bf16x8;
typedef __attribute__((ext_vector_type(4))) float f32x4;
typedef unsigned short ushort_t;

__device__ __forceinline__ ushort_t f2bf(float f) {
  unsigned u = __float_as_uint(f);
  u += 0x7fffu + ((u >> 16) & 1u);
  return (ushort_t)(u >> 16);
}

__device__ __forceinline__ float bf2f(ushort_t b) {
  return __uint_as_float(((unsigned)b) << 16);
}

__device__ __forceinline__ f32x4 mfma16(bf16x8 a, bf16x8 b, f32x4 c) {
  return __builtin_amdgcn_mfma_f32_16x16x32_bf16(a, b, c, 0, 0, 0);
}

// XOR swizzle for 8-chunk (64-col) bf16 LDS rows
__device__ __forceinline__ int swz(int r) { return (r ^ (r >> 3)) & 7; }

__device__ __forceinline__ void gload16(const void* g, void* l) {
  __builtin_amdgcn_global_load_lds(
      (const __attribute__((address_space(1))) unsigned int*)g,
      (__attribute__((address_space(3))) unsigned int*)l, 16, 0, 0);
}

// ------- Fused prep: LN (0..8191) + wtrans (8192..10495) + pos->bf16*QSCALE --
__global__ __launch_bounds__(256) void prep_kernel(
    const float* __restrict__ x, const float* __restrict__ gamma,
    const float* __restrict__ beta, ushort_t* __restrict__ xn,
    const float* __restrict__ Wq, const float* __restrict__ Wk,
    const float* __restrict__ Wv, const float* __restrict__ Wo,
    ushort_t* __restrict__ wt,
    const float* __restrict__ pos, ushort_t* __restrict__ posb) {
  __shared__ float red[8];
  __shared__ float tile[32][33];
  const int bid = blockIdx.x;
  const int tid = threadIdx.x;

  if (bid < TOK) {
    // ---------------- LayerNorm: 1 block per token ----------------
    const float* row = x + (size_t)bid * CDIM;
    float v[3];
    float s = 0.f, s2 = 0.f;
#pragma unroll
    for (int i = 0; i < 3; i++) {
      v[i] = row[tid + 256 * i];
      s += v[i];
      s2 += v[i] * v[i];
    }
#pragma unroll
    for (int off = 32; off; off >>= 1) {
      s += __shfl_xor(s, off);
      s2 += __shfl_xor(s2, off);
    }
    int wid = tid >> 6, lane = tid & 63;
    if (lane == 0) { red[wid] = s; red[wid + 4] = s2; }
    __syncthreads();
    s = red[0] + red[1] + red[2] + red[3];
    s2 = red[4] + red[5] + red[6] + red[7];
    float mu = s * (1.f / CDIM);
    float var = s2 * (1.f / CDIM) - mu * mu;
    float rstd = rsqrtf(var + 1e-5f);
    ushort_t* orow = xn + (size_t)bid * CDIM;
#pragma unroll
    for (int i = 0; i < 3; i++) {
      int c = tid + 256 * i;
      orow[c] = f2bf((v[i] - mu) * rstd * gamma[c] + beta[c]);
    }
  } else if (bid < TOK + 2304) {
    // ------- weight transpose: wt[z][n][k] = W_z[k][n], 32x32 tiles -------
    int zi = bid - TOK;
    int z = zi / 576;
    int rem = zi % 576;
    int trr = rem / 24, tcc = rem % 24;
    const float* W = (z == 0) ? Wq : (z == 1) ? Wk : (z == 2) ? Wv : Wo;
    int tx = tid & 31, ty = tid >> 5;
#pragma unroll
    for (int j = 0; j < 4; j++) {
      int k = trr * 32 + ty + j * 8;
      tile[ty + j * 8][tx] = W[(size_t)k * CDIM + tcc * 32 + tx];
    }
    __syncthreads();
    ushort_t* o = wt + (size_t)z * CDIM * CDIM;
#pragma unroll
    for (int j = 0; j < 4; j++) {
      int n = tcc * 32 + ty + j * 8;
      o[(size_t)n * CDIM + trr * 32 + tx] = f2bf(tile[tx][ty + j * 8]);
    }
  } else {
    // ---- pos -> bf16(pos*QSCALE), vectorized: 2048 elems/block, 8/thread ----
    size_t base = (size_t)(bid - TOK - 2304) * 2048 + (size_t)tid * 8;
    float p[8];
    *reinterpret_cast<float4*>(&p[0]) = *reinterpret_cast<const float4*>(&pos[base]);
    *reinterpret_cast<float4*>(&p[4]) = *reinterpret_cast<const float4*>(&pos[base + 4]);
    uint4 d;
    unsigned* dw = reinterpret_cast<unsigned*>(&d);
#pragma unroll
    for (int j = 0; j < 4; j++)
      dw[j] = (unsigned)f2bf(p[2 * j] * QSCALE) |
              ((unsigned)f2bf(p[2 * j + 1] * QSCALE) << 16);
    *reinterpret_cast<uint4*>(&posb[base]) = d;
  }
}

// -------- QKV GEMM: 3 N=768 panels + LDS-bounce; pos added COALESCED ---------
// Bounce (z==0) stores bf16((acc+bq)*QSCALE), no global reads. The coalesced
// store phase loads posb as uint4 (streaming BW) and adds elementwise --
// scattered posb reads (r23's 10us regression) eliminated.
__global__ __launch_bounds__(256) void gemm0_kernel(
    const ushort_t* __restrict__ A, const ushort_t* __restrict__ wt,
    const float* __restrict__ bq, const float* __restrict__ bk,
    const float* __restrict__ bv, const ushort_t* __restrict__ posb,
    ushort_t* __restrict__ outp) {
  __shared__ __align__(16) ushort_t smem[32768];  // 64KB: staging + bounce
  ushort_t* lds_a0 = smem;                 // [2][128*64] A buffers
  ushort_t* lds_b0 = smem + 16384;         // [2][128*64] B buffers
  const int NB = 6;
  const int z = blockIdx.x / 384;          // QKV panel (runs ~sequentially)
  const int lin2 = blockIdx.x % 384;
  // within-panel XCD-chunked swizzle (384 % 8 == 0)
  int nl = (lin2 & 7) * 48 + (lin2 >> 3);
  const int bn = nl % NB, bm = nl / NB;
  const ushort_t* Bt = wt + (size_t)z * CDIM * CDIM;

  const int tid = threadIdx.x;
  const int lane = tid & 63, wid = tid >> 6;
  const int wr = wid >> 1, wc = wid & 1;
  const int l16 = lane & 15, lg = lane >> 4;
  f32x4 acc[4][4] = {};

  int aoff[2][4], boff[2][4];
#pragma unroll
  for (int kk = 0; kk < 2; kk++) {
#pragma unroll
    for (int mi = 0; mi < 4; mi++) {
      int r = wr * 64 + mi * 16 + l16;
      aoff[kk][mi] = r * 64 + (((kk * 4 + lg) ^ swz(r)) & 7) * 8;
    }
#pragma unroll
    for (int ni = 0; ni < 4; ni++) {
      int r = wc * 64 + ni * 16 + l16;
      boff[kk][ni] = r * 64 + (((kk * 4 + lg) ^ swz(r)) & 7) * 8;
    }
  }

  auto stage = [&](int buf, int k0) {
#pragma unroll
    for (int i = 0; i < 4; i++) {
      int slot = i * 256 + tid;
      int row = slot >> 3, j = slot & 7;
      int c8 = ((j ^ swz(row)) & 7) * 8;  // pre-swizzled source column
      gload16(&A[(size_t)(bm * 128 + row) * CDIM + k0 + c8],
              &lds_a0[buf * 8192 + slot * 8]);
      gload16(&Bt[(size_t)(bn * 128 + row) * CDIM + k0 + c8],
              &lds_b0[buf * 8192 + slot * 8]);
    }
  };

  stage(0, 0);
  asm volatile("s_waitcnt vmcnt(0)" ::: "memory");
  __builtin_amdgcn_s_barrier();
  __builtin_amdgcn_sched_barrier(0);

  int cur = 0;
#pragma unroll 2
  for (int t = 0; t < 12; t++) {
    if (t < 11) stage(cur ^ 1, (t + 1) * 64);  // issue next tile early
#pragma unroll
    for (int kk = 0; kk < 2; kk++) {
      bf16x8 af[4], bfr[4];
#pragma unroll
      for (int mi = 0; mi < 4; mi++)
        af[mi] = *reinterpret_cast<const bf16x8*>(&lds_a0[cur * 8192 + aoff[kk][mi]]);
#pragma unroll
      for (int ni = 0; ni < 4; ni++)
        bfr[ni] = *reinterpret_cast<const bf16x8*>(&lds_b0[cur * 8192 + boff[kk][ni]]);
      __builtin_amdgcn_s_setprio(1);
#pragma unroll
      for (int mi = 0; mi < 4; mi++)
#pragma unroll
        for (int ni = 0; ni < 4; ni++)
          acc[mi][ni] = mfma16(af[mi], bfr[ni], acc[mi][ni]);
      __builtin_amdgcn_s_setprio(0);
    }
    asm volatile("s_waitcnt vmcnt(0) lgkmcnt(0)" ::: "memory");
    __builtin_amdgcn_s_barrier();
    __builtin_amdgcn_sched_barrier(0);
    cur ^= 1;
  }

  // ---- epilogue: full LDS fence, bias bounce (no global reads) ----
  __syncthreads();  // REAL memory fence: no ds_write may precede it
  const int BST = 136;  // row stride in ushorts; 136%8==0 keeps 16B alignment
#pragma unroll
  for (int mi = 0; mi < 4; mi++)
#pragma unroll
    for (int ni = 0; ni < 4; ni++)
#pragma unroll
      for (int r = 0; r < 4; r++) {
        int lrow = wr * 64 + mi * 16 + 4 * lg + r;
        int lcol = wc * 64 + ni * 16 + l16;
        int gcol = bn * 128 + lcol;
        float v = acc[mi][ni][r];
        if (z == 0) {
          v = (v + bq[gcol]) * QSCALE;  // pos added in coalesced phase below
        } else if (z == 1) {
          v += bk[gcol];
        } else {
          v += bv[gcol];
        }
        smem[lrow * BST + lcol] = f2bf(v);
      }
  __syncthreads();
  {
    int lrow = tid >> 1, half = (tid & 1) * 64;
    int grow = bm * 128 + lrow;
    ushort_t* dst = &outp[(size_t)grow * QKV_N + z * CDIM + bn * 128 + half];
    const ushort_t* src = &smem[lrow * BST + half];
    if (z == 0) {
      const ushort_t* pb = &posb[(size_t)grow * CDIM + bn * 128 + half];
#pragma unroll
      for (int j = 0; j < 8; j++) {
        uint4 qv = *reinterpret_cast<const uint4*>(&src[j * 8]);
        uint4 pv = *reinterpret_cast<const uint4*>(&pb[j * 8]);
        uint4 o;
        const unsigned* qd = reinterpret_cast<const unsigned*>(&qv);
        const unsigned* pd = reinterpret_cast<const unsigned*>(&pv);
        unsigned* od = reinterpret_cast<unsigned*>(&o);
#pragma unroll
        for (int u = 0; u < 4; u++) {
          float lo = __uint_as_float(qd[u] << 16) + __uint_as_float(pd[u] << 16);
          float hi = __uint_as_float(qd[u] & 0xffff0000u) +
                     __uint_as_float(pd[u] & 0xffff0000u);
          unsigned pk;
          asm("v_cvt_pk_bf16_f32 %0, %1, %2" : "=v"(pk) : "v"(lo), "v"(hi));
          od[u] = pk;
        }
        *reinterpret_cast<uint4*>(&dst[j * 8]) = o;
      }
    } else {
#pragma unroll
      for (int j = 0; j < 8; j++)
        *reinterpret_cast<uint4*>(&dst[j * 8]) =
            *reinterpret_cast<const uint4*>(&src[j * 8]);
    }
  }
}

// -------- out-proj GEMM (r10-proven 128^2 BK=64 overlapped dbuf) -------------
__global__ __launch_bounds__(256) void gemm1_kernel(
    const ushort_t* __restrict__ A, const ushort_t* __restrict__ Bt,
    const float* __restrict__ b0, const float* __restrict__ extra,
    float* __restrict__ outp) {
  __shared__ __align__(16) ushort_t lds_a[2][128 * 64];
  __shared__ __align__(16) ushort_t lds_b[2][128 * 64];
  const int NB = 6;
  int lin = blockIdx.y * NB + blockIdx.x;
  int nl = (lin & 7) * (NB * 8) + (lin >> 3);
  const int bn = nl % NB, bm = nl / NB;

  const int tid = threadIdx.x;
  const int lane = tid & 63, wid = tid >> 6;
  const int wr = wid >> 1, wc = wid & 1;
  const int l16 = lane & 15, lg = lane >> 4;
  f32x4 acc[4][4] = {};

  int aoff[2][4], boff[2][4];
#pragma unroll
  for (int kk = 0; kk < 2; kk++) {
#pragma unroll
    for (int mi = 0; mi < 4; mi++) {
      int r = wr * 64 + mi * 16 + l16;
      aoff[kk][mi] = r * 64 + (((kk * 4 + lg) ^ swz(r)) & 7) * 8;
    }
#pragma unroll
    for (int ni = 0; ni < 4; ni++) {
      int r = wc * 64 + ni * 16 + l16;
      boff[kk][ni] = r * 64 + (((kk * 4 + lg) ^ swz(r)) & 7) * 8;
    }
  }

  auto stage = [&](int buf, int k0) {
#pragma unroll
    for (int i = 0; i < 4; i++) {
      int slot = i * 256 + tid;
      int row = slot >> 3, j = slot & 7;
      int c8 = ((j ^ swz(row)) & 7) * 8;
      gload16(&A[(size_t)(bm * 128 + row) * CDIM + k0 + c8], &lds_a[buf][slot * 8]);
      gload16(&Bt[(size_t)(bn * 128 + row) * CDIM + k0 + c8], &lds_b[buf][slot * 8]);
    }
  };

  stage(0, 0);
  asm volatile("s_waitcnt vmcnt(0)" ::: "memory");
  __builtin_amdgcn_s_barrier();
  __builtin_amdgcn_sched_barrier(0);

  int cur = 0;
#pragma unroll 2
  for (int t = 0; t < 12; t++) {
    if (t < 11) stage(cur ^ 1, (t + 1) * 64);
#pragma unroll
    for (int kk = 0; kk < 2; kk++) {
      bf16x8 af[4], bfr[4];
#pragma unroll
      for (int mi = 0; mi < 4; mi++)
        af[mi] = *reinterpret_cast<const bf16x8*>(&lds_a[cur][aoff[kk][mi]]);
#pragma unroll
      for (int ni = 0; ni < 4; ni++)
        bfr[ni] = *reinterpret_cast<const bf16x8*>(&lds_b[cur][boff[kk][ni]]);
      __builtin_amdgcn_s_setprio(1);
#pragma unroll
      for (int mi = 0; mi < 4; mi++)
#pragma unroll
        for (int ni = 0; ni < 4; ni++)
          acc[mi][ni] = mfma16(af[mi], bfr[ni], acc[mi][ni]);
      __builtin_amdgcn_s_setprio(0);
    }
    asm volatile("s_waitcnt vmcnt(0) lgkmcnt(0)" ::: "memory");
    __builtin_amdgcn_s_barrier();
    __builtin_amdgcn_sched_barrier(0);
    cur ^= 1;
  }

#pragma unroll
  for (int mi = 0; mi < 4; mi++)
#pragma unroll
    for (int ni = 0; ni < 4; ni++)
#pragma unroll
      for (int r = 0; r < 4; r++) {
        int grow = bm * 128 + wr * 64 + mi * 16 + 4 * lg + r;
        int gcol = bn * 128 + wc * 64 + ni * 16 + l16;
        outp[(size_t)grow * CDIM + gcol] =
            acc[mi][ni][r] + b0[gcol] + extra[(size_t)grow * CDIM + gcol];
      }
}

// -------- Flash attention v9: K-in-LDS, QBLK=128 (no pos) --------------------
__global__ __launch_bounds__(256, 3) void attn_kernel(const ushort_t* __restrict__ QKV,
                                                      ushort_t* __restrict__ O) {
  const int b = blockIdx.x, h = blockIdx.y, qt = blockIdx.z;

  const int tid = threadIdx.x, lane = tid & 63, w = tid >> 6;
  const int l16 = lane & 15, lg = lane >> 4;
  const int tb = b * 1024 + qt * 128;
  const int co_q = h * HD, co_k = CDIM + h * HD, co_v = 2 * CDIM + h * HD;

  __shared__ __align__(16) ushort_t k_lds[2][64 * 64];
  __shared__ __align__(16) ushort_t vt_lds[2][64 * 64];
  __shared__ __align__(16) ushort_t p_lds[128 * 64];

  bf16x8 qf[2][2];
#pragma unroll
  for (int mi = 0; mi < 2; mi++)
#pragma unroll
    for (int ds = 0; ds < 2; ds++)
      qf[mi][ds] = *reinterpret_cast<const bf16x8*>(
          &QKV[(size_t)(tb + w * 32 + mi * 16 + l16) * QKV_N + co_q + ds * 32 + 8 * lg]);

  float m_sm[2] = {MREF, MREF};
  float l_sm[2] = {0.f, 0.f};
  float m_acc[2][4];
#pragma unroll
  for (int mi = 0; mi < 2; mi++)
#pragma unroll
    for (int r = 0; r < 4; r++) m_acc[mi][r] = MREF;
  f32x4 oacc[2][4] = {};

  int kfoff[2][4];
#pragma unroll
  for (int ds = 0; ds < 2; ds++)
#pragma unroll
    for (int ni = 0; ni < 4; ni++) {
      int rr = ni * 16 + l16;
      kfoff[ds][ni] = rr * 64 + (((ds * 4 + lg) ^ swz(rr)) & 7) * 8;
    }
  int poff[2][4], paoff[2][2];
#pragma unroll
  for (int mi = 0; mi < 2; mi++) {
    int myq = w * 32 + mi * 16 + l16;
    int sq = swz(myq);
#pragma unroll
    for (int ni = 0; ni < 4; ni++)
      poff[mi][ni] = myq * 64 + (lg & 1) * 4 + (((ni * 2 + (lg >> 1)) ^ sq) & 7) * 8;
#pragma unroll
    for (int ks = 0; ks < 2; ks++)
      paoff[mi][ks] = myq * 64 + (((ks * 4 + lg) ^ sq) & 7) * 8;
  }
  int vboff[2][4];
#pragma unroll
  for (int ks = 0; ks < 2; ks++)
#pragma unroll
    for (int ni = 0; ni < 4; ni++) {
      int d = ni * 16 + l16;
      vboff[ks][ni] = d * 64 + (((ks * 4 + lg) ^ swz(d)) & 7) * 8;
    }

  auto stage_k = [&](int buf, int kt) {
    const int kv0 = kt * 64;
#pragma unroll
    for (int i = 0; i < 2; i++) {
      int slot = i * 256 + tid;
      int r = slot >> 3, j = slot & 7;
      int c = ((j ^ swz(r)) & 7) * 8;
      gload16(&QKV[(size_t)(b * 1024 + kv0 + r) * QKV_N + co_k + c],
              &k_lds[buf][slot * 8]);
    }
  };

  const int kv0 = (tid >> 3) * 2, d0 = (tid & 7) * 8;
  const int sV = ((kv0 >> 3) ^ (d0 >> 3)) & 7;
  int voff[8];
#pragma unroll
  for (int u = 0; u < 8; u++)
    voff[u] = (d0 + u) * 64 + ((sV ^ u) & 7) * 8 + (kv0 & 7);
  const ushort_t* vsrc = QKV + (size_t)(b * 1024 + kv0) * QKV_N + co_v + d0;

  uint4 vr0, vr1;
  auto load_v = [&](int kt) {
    vr0 = *reinterpret_cast<const uint4*>(vsrc + (size_t)kt * 64 * QKV_N);
    vr1 = *reinterpret_cast<const uint4*>(vsrc + (size_t)kt * 64 * QKV_N + QKV_N);
  };
  auto write_v = [&](int buf) {
    const unsigned* w0 = reinterpret_cast<const unsigned*>(&vr0);
    const unsigned* w1 = reinterpret_cast<const unsigned*>(&vr1);
#pragma unroll
    for (int u = 0; u < 8; u++) {
      unsigned a = w0[u >> 1], c = w1[u >> 1];
      unsigned val = (u & 1) ? ((a >> 16) | (c & 0xffff0000u))
                             : ((a & 0xffffu) | (c << 16));
      *reinterpret_cast<unsigned*>(&vt_lds[buf][voff[u]]) = val;
    }
  };

  stage_k(0, 0);
  load_v(0);
  write_v(0);
  asm volatile("s_waitcnt vmcnt(0) lgkmcnt(0)" ::: "memory");
  __builtin_amdgcn_s_barrier();
  __builtin_amdgcn_sched_barrier(0);

  for (int kt = 0; kt < 16; kt++) {
    const int cur = kt & 1, nxt = cur ^ 1;
    if (kt < 15) { stage_k(nxt, kt + 1); load_v(kt + 1); }

    bf16x8 kf[2][4];
#pragma unroll
    for (int ds = 0; ds < 2; ds++)
#pragma unroll
      for (int ni = 0; ni < 4; ni++)
        kf[ds][ni] = *reinterpret_cast<const bf16x8*>(&k_lds[cur][kfoff[ds][ni]]);

#pragma unroll
    for (int mi = 0; mi < 2; mi++) {
      f32x4 st[4] = {};
      __builtin_amdgcn_s_setprio(1);
#pragma unroll
      for (int ds = 0; ds < 2; ds++)
#pragma unroll
        for (int ni = 0; ni < 4; ni++)
          st[ni] = mfma16(kf[ds][ni], qf[mi][ds], st[ni]);
      __builtin_amdgcn_s_setprio(0);

      float t0 = fmaxf(fmaxf(st[0][0], st[0][1]), fmaxf(st[0][2], st[0][3]));
      float t1 = fmaxf(fmaxf(st[1][0], st[1][1]), fmaxf(st[1][2], st[1][3]));
      float t2 = fmaxf(fmaxf(st[2][0], st[2][1]), fmaxf(st[2][2], st[2][3]));
      float t3 = fmaxf(fmaxf(st[3][0], st[3][1]), fmaxf(st[3][2], st[3][3]));
      float tm = fmaxf(fmaxf(t0, t1), fmaxf(t2, t3));

      if (__any(tm > m_sm[mi])) {
        float rm = fmaxf(tm, __shfl_xor(tm, 16));
        rm = fmaxf(rm, __shfl_xor(rm, 32));
        float mnew = fmaxf(m_sm[mi], rm);
        l_sm[mi] *= exp2f(m_sm[mi] - mnew);
        m_sm[mi] = mnew;
#pragma unroll
        for (int r = 0; r < 4; r++) {
          float mn = __shfl(mnew, 4 * lg + r);
          float corr = exp2f(m_acc[mi][r] - mn);
          m_acc[mi][r] = mn;
#pragma unroll
          for (int ni = 0; ni < 4; ni++) oacc[mi][ni][r] *= corr;
        }
      }

      float ps[4];
#pragma unroll
      for (int ni = 0; ni < 4; ni++) {
        float e0 = exp2f(st[ni][0] - m_sm[mi]);
        float e1 = exp2f(st[ni][1] - m_sm[mi]);
        float e2 = exp2f(st[ni][2] - m_sm[mi]);
        float e3 = exp2f(st[ni][3] - m_sm[mi]);
        st[ni][0] = e0; st[ni][1] = e1; st[ni][2] = e2; st[ni][3] = e3;
        ps[ni] = (e0 + e1) + (e2 + e3);
      }
      l_sm[mi] += (ps[0] + ps[1]) + (ps[2] + ps[3]);

#pragma unroll
      for (int ni = 0; ni < 4; ni++) {
        unsigned p01, p23;
        asm("v_cvt_pk_bf16_f32 %0, %1, %2" : "=v"(p01) : "v"(st[ni][0]), "v"(st[ni][1]));
        asm("v_cvt_pk_bf16_f32 %0, %1, %2" : "=v"(p23) : "v"(st[ni][2]), "v"(st[ni][3]));
        uint2 pk; pk.x = p01; pk.y = p23;
        *reinterpret_cast<uint2*>(&p_lds[poff[mi][ni]]) = pk;
      }
    }

#pragma unroll
    for (int ks = 0; ks < 2; ks++) {
      bf16x8 pa0 = *reinterpret_cast<const bf16x8*>(&p_lds[paoff[0][ks]]);
      bf16x8 pa1 = *reinterpret_cast<const bf16x8*>(&p_lds[paoff[1][ks]]);
      bf16x8 vb[4];
#pragma unroll
      for (int ni = 0; ni < 4; ni++)
        vb[ni] = *reinterpret_cast<const bf16x8*>(&vt_lds[cur][vboff[ks][ni]]);
      __builtin_amdgcn_s_setprio(1);
#pragma unroll
      for (int ni = 0; ni < 4; ni++) {
        oacc[0][ni] = mfma16(pa0, vb[ni], oacc[0][ni]);
        oacc[1][ni] = mfma16(pa1, vb[ni], oacc[1][ni]);
      }
      __builtin_amdgcn_s_setprio(0);
    }

    if (kt < 15) write_v(nxt);
    asm volatile("s_waitcnt vmcnt(0) lgkmcnt(0)" ::: "memory");
    __builtin_amdgcn_s_barrier();
    __builtin_amdgcn_sched_barrier(0);
  }

#pragma unroll
  for (int mi = 0; mi < 2; mi++) {
    float l = l_sm[mi];
    l += __shfl_xor(l, 16);
    l += __shfl_xor(l, 32);
#pragma unroll
    for (int r = 0; r < 4; r++) {
      float lr = __shfl(l, 4 * lg + r);
      float inv = 1.f / lr;
      int grow = tb + w * 32 + mi * 16 + 4 * lg + r;
#pragma unroll
      for (int ni = 0; ni < 4; ni++) {
        int gcol = h * HD + ni * 16 + l16;
        O[(size_t)grow * CDIM + gcol] = f2bf(oacc[mi][ni][r] * inv);
      }
    }
  }
}

extern "C" void kernel_launch(void* const* d_in, const int* in_sizes, int n_in,
                              void* d_out, int out_size, void* d_ws, size_t ws_size,
                              hipStream_t stream) {
  const float* x     = (const float*)d_in[0];
  const float* pos   = (const float*)d_in[1];
  const float* gamma = (const float*)d_in[2];
  const float* beta  = (const float*)d_in[3];
  const float* Wq    = (const float*)d_in[4];
  const float* bq    = (const float*)d_in[5];
  const float* Wk    = (const float*)d_in[6];
  const float* bk    = (const float*)d_in[7];
  const float* Wv    = (const float*)d_in[8];
  const float* bv    = (const float*)d_in[9];
  const float* Wo    = (const float*)d_in[10];
  const float* bo    = (const float*)d_in[11];
  float* out = (float*)d_out;

  ushort_t* xn   = (ushort_t*)d_ws;                    // 8192*768
  ushort_t* wt   = xn + (size_t)TOK * CDIM;            // 3072*768 (q,k,v,o transposed)
  ushort_t* qkv  = wt + (size_t)3072 * CDIM;           // 8192*2304
  ushort_t* aout = qkv + (size_t)TOK * QKV_N;          // 8192*768
  ushort_t* posb = aout + (size_t)TOK * CDIM;          // 8192*768 (pos*QSCALE bf16)

  prep_kernel<<<TOK + 2304 + 3072, 256, 0, stream>>>(x, gamma, beta, xn,
                                                     Wq, Wk, Wv, Wo, wt,
                                                     pos, posb);
  gemm0_kernel<<<1152, 256, 0, stream>>>(xn, wt, bq, bk, bv, posb, qkv);
  attn_kernel<<<dim3(8, NH, 8), 256, 0, stream>>>(qkv, aout);
  gemm1_kernel<<<dim3(6, 64), 256, 0, stream>>>(aout, wt + (size_t)QKV_N * CDIM,
                                                bo, x, out);
}

// Round 25
// 152.251 us; speedup vs baseline: 1.0560x; 1.0205x over previous
//
#include <hip/hip_runtime.h>
#include <hip/hip_bf16.h>

#define TOK 8192
#define CDIM 768
#define NH 12
#define HD 64
#define QKV_N 2304
// 0.125 * log2(e): QK^T scale folded into Q, softmax runs in exp2 domain
#define QSCALE 0.18033688011f
// deferred-max reference (exp2 domain): P = 2^(S' - MREF) <= 1 for S' <= MREF
#define MREF 10.0f

typedef __attribute__((ext_vector_type(8))) short bf16x8;
typedef __attribute__((ext_vector_type(4))) float f32x4;
typedef unsigned short ushort_t;

__device__ __forceinline__ ushort_t f2bf(float f) {
  unsigned u = __float_as_uint(f);
  u += 0x7fffu + ((u >> 16) & 1u);
  return (ushort_t)(u >> 16);
}

__device__ __forceinline__ float bf2f(ushort_t b) {
  return __uint_as_float(((unsigned)b) << 16);
}

__device__ __forceinline__ f32x4 mfma16(bf16x8 a, bf16x8 b, f32x4 c) {
  return __builtin_amdgcn_mfma_f32_16x16x32_bf16(a, b, c, 0, 0, 0);
}

// XOR swizzle for 8-chunk (64-col) bf16 LDS rows
__device__ __forceinline__ int swz(int r) { return (r ^ (r >> 3)) & 7; }

__device__ __forceinline__ void gload16(const void* g, void* l) {
  __builtin_amdgcn_global_load_lds(
      (const __attribute__((address_space(1))) unsigned int*)g,
      (__attribute__((address_space(3))) unsigned int*)l, 16, 0, 0);
}

// ------- Fused prep: LN (blocks 0..8191) + weight transpose (8192..10495) ----
__global__ __launch_bounds__(256) void prep_kernel(
    const float* __restrict__ x, const float* __restrict__ gamma,
    const float* __restrict__ beta, ushort_t* __restrict__ xn,
    const float* __restrict__ Wq, const float* __restrict__ Wk,
    const float* __restrict__ Wv, const float* __restrict__ Wo,
    ushort_t* __restrict__ wt) {
  __shared__ float red[8];
  __shared__ float tile[32][33];
  const int bid = blockIdx.x;
  const int tid = threadIdx.x;

  if (bid < TOK) {
    // ---------------- LayerNorm: 1 block per token ----------------
    const float* row = x + (size_t)bid * CDIM;
    float v[3];
    float s = 0.f, s2 = 0.f;
#pragma unroll
    for (int i = 0; i < 3; i++) {
      v[i] = row[tid + 256 * i];
      s += v[i];
      s2 += v[i] * v[i];
    }
#pragma unroll
    for (int off = 32; off; off >>= 1) {
      s += __shfl_xor(s, off);
      s2 += __shfl_xor(s2, off);
    }
    int wid = tid >> 6, lane = tid & 63;
    if (lane == 0) { red[wid] = s; red[wid + 4] = s2; }
    __syncthreads();
    s = red[0] + red[1] + red[2] + red[3];
    s2 = red[4] + red[5] + red[6] + red[7];
    float mu = s * (1.f / CDIM);
    float var = s2 * (1.f / CDIM) - mu * mu;
    float rstd = rsqrtf(var + 1e-5f);
    ushort_t* orow = xn + (size_t)bid * CDIM;
#pragma unroll
    for (int i = 0; i < 3; i++) {
      int c = tid + 256 * i;
      orow[c] = f2bf((v[i] - mu) * rstd * gamma[c] + beta[c]);
    }
  } else {
    // ------- weight transpose: wt[z][n][k] = W_z[k][n], 32x32 tiles -------
    int zi = bid - TOK;
    int z = zi / 576;
    int rem = zi % 576;
    int trr = rem / 24, tcc = rem % 24;
    const float* W = (z == 0) ? Wq : (z == 1) ? Wk : (z == 2) ? Wv : Wo;
    int tx = tid & 31, ty = tid >> 5;
#pragma unroll
    for (int j = 0; j < 4; j++) {
      int k = trr * 32 + ty + j * 8;
      tile[ty + j * 8][tx] = W[(size_t)k * CDIM + tcc * 32 + tx];
    }
    __syncthreads();
    ushort_t* o = wt + (size_t)z * CDIM * CDIM;
#pragma unroll
    for (int j = 0; j < 4; j++) {
      int n = tcc * 32 + ty + j * 8;
      o[(size_t)n * CDIM + trr * 32 + tx] = f2bf(tile[tx][ty + j * 8]);
    }
  }
}

// -------- QKV GEMM: 3 sequential N=768 panels + LDS-bounce epilogue ----------
// __syncthreads() fences (r22 race fix). No pos traffic (added in attn).
__global__ __launch_bounds__(256) void gemm0_kernel(
    const ushort_t* __restrict__ A, const ushort_t* __restrict__ wt,
    const float* __restrict__ bq, const float* __restrict__ bk,
    const float* __restrict__ bv,
    ushort_t* __restrict__ outp) {
  __shared__ __align__(16) ushort_t smem[32768];  // 64KB: staging + bounce
  ushort_t* lds_a0 = smem;                 // [2][128*64] A buffers
  ushort_t* lds_b0 = smem + 16384;         // [2][128*64] B buffers
  const int NB = 6;
  const int z = blockIdx.x / 384;          // QKV panel (runs ~sequentially)
  const int lin2 = blockIdx.x % 384;
  // within-panel XCD-chunked swizzle (384 % 8 == 0)
  int nl = (lin2 & 7) * 48 + (lin2 >> 3);
  const int bn = nl % NB, bm = nl / NB;
  const ushort_t* Bt = wt + (size_t)z * CDIM * CDIM;

  const int tid = threadIdx.x;
  const int lane = tid & 63, wid = tid >> 6;
  const int wr = wid >> 1, wc = wid & 1;
  const int l16 = lane & 15, lg = lane >> 4;
  f32x4 acc[4][4] = {};

  int aoff[2][4], boff[2][4];
#pragma unroll
  for (int kk = 0; kk < 2; kk++) {
#pragma unroll
    for (int mi = 0; mi < 4; mi++) {
      int r = wr * 64 + mi * 16 + l16;
      aoff[kk][mi] = r * 64 + (((kk * 4 + lg) ^ swz(r)) & 7) * 8;
    }
#pragma unroll
    for (int ni = 0; ni < 4; ni++) {
      int r = wc * 64 + ni * 16 + l16;
      boff[kk][ni] = r * 64 + (((kk * 4 + lg) ^ swz(r)) & 7) * 8;
    }
  }

  auto stage = [&](int buf, int k0) {
#pragma unroll
    for (int i = 0; i < 4; i++) {
      int slot = i * 256 + tid;
      int row = slot >> 3, j = slot & 7;
      int c8 = ((j ^ swz(row)) & 7) * 8;  // pre-swizzled source column
      gload16(&A[(size_t)(bm * 128 + row) * CDIM + k0 + c8],
              &lds_a0[buf * 8192 + slot * 8]);
      gload16(&Bt[(size_t)(bn * 128 + row) * CDIM + k0 + c8],
              &lds_b0[buf * 8192 + slot * 8]);
    }
  };

  stage(0, 0);
  asm volatile("s_waitcnt vmcnt(0)" ::: "memory");
  __builtin_amdgcn_s_barrier();
  __builtin_amdgcn_sched_barrier(0);

  int cur = 0;
#pragma unroll 2
  for (int t = 0; t < 12; t++) {
    if (t < 11) stage(cur ^ 1, (t + 1) * 64);  // issue next tile early
#pragma unroll
    for (int kk = 0; kk < 2; kk++) {
      bf16x8 af[4], bfr[4];
#pragma unroll
      for (int mi = 0; mi < 4; mi++)
        af[mi] = *reinterpret_cast<const bf16x8*>(&lds_a0[cur * 8192 + aoff[kk][mi]]);
#pragma unroll
      for (int ni = 0; ni < 4; ni++)
        bfr[ni] = *reinterpret_cast<const bf16x8*>(&lds_b0[cur * 8192 + boff[kk][ni]]);
      __builtin_amdgcn_s_setprio(1);
#pragma unroll
      for (int mi = 0; mi < 4; mi++)
#pragma unroll
        for (int ni = 0; ni < 4; ni++)
          acc[mi][ni] = mfma16(af[mi], bfr[ni], acc[mi][ni]);
      __builtin_amdgcn_s_setprio(0);
    }
    asm volatile("s_waitcnt vmcnt(0) lgkmcnt(0)" ::: "memory");
    __builtin_amdgcn_s_barrier();
    __builtin_amdgcn_sched_barrier(0);
    cur ^= 1;
  }

  // ---- epilogue: full LDS fence, then bias -> bf16 bounce -> coalesced ----
  __syncthreads();  // REAL memory fence: no ds_write may precede it
  const int BST = 136;  // row stride in ushorts; 136%8==0 keeps 16B alignment
#pragma unroll
  for (int mi = 0; mi < 4; mi++)
#pragma unroll
    for (int ni = 0; ni < 4; ni++)
#pragma unroll
      for (int r = 0; r < 4; r++) {
        int lrow = wr * 64 + mi * 16 + 4 * lg + r;
        int lcol = wc * 64 + ni * 16 + l16;
        int gcol = bn * 128 + lcol;
        float v = acc[mi][ni][r];
        if (z == 0) {
          v = (v + bq[gcol]) * QSCALE;  // pos added in attn prologue
        } else if (z == 1) {
          v += bk[gcol];
        } else {
          v += bv[gcol];
        }
        smem[lrow * BST + lcol] = f2bf(v);
      }
  __syncthreads();
  {
    int lrow = tid >> 1, half = (tid & 1) * 64;
    int grow = bm * 128 + lrow;
    ushort_t* dst = &outp[(size_t)grow * QKV_N + z * CDIM + bn * 128 + half];
    const ushort_t* src = &smem[lrow * BST + half];
#pragma unroll
    for (int j = 0; j < 8; j++)
      *reinterpret_cast<uint4*>(&dst[j * 8]) =
          *reinterpret_cast<const uint4*>(&src[j * 8]);
  }
}

// -------- out-proj GEMM (r10-proven 128^2 BK=64 overlapped dbuf) -------------
__global__ __launch_bounds__(256) void gemm1_kernel(
    const ushort_t* __restrict__ A, const ushort_t* __restrict__ Bt,
    const float* __restrict__ b0, const float* __restrict__ extra,
    float* __restrict__ outp) {
  __shared__ __align__(16) ushort_t lds_a[2][128 * 64];
  __shared__ __align__(16) ushort_t lds_b[2][128 * 64];
  const int NB = 6;
  int lin = blockIdx.y * NB + blockIdx.x;
  int nl = (lin & 7) * (NB * 8) + (lin >> 3);
  const int bn = nl % NB, bm = nl / NB;

  const int tid = threadIdx.x;
  const int lane = tid & 63, wid = tid >> 6;
  const int wr = wid >> 1, wc = wid & 1;
  const int l16 = lane & 15, lg = lane >> 4;
  f32x4 acc[4][4] = {};

  int aoff[2][4], boff[2][4];
#pragma unroll
  for (int kk = 0; kk < 2; kk++) {
#pragma unroll
    for (int mi = 0; mi < 4; mi++) {
      int r = wr * 64 + mi * 16 + l16;
      aoff[kk][mi] = r * 64 + (((kk * 4 + lg) ^ swz(r)) & 7) * 8;
    }
#pragma unroll
    for (int ni = 0; ni < 4; ni++) {
      int r = wc * 64 + ni * 16 + l16;
      boff[kk][ni] = r * 64 + (((kk * 4 + lg) ^ swz(r)) & 7) * 8;
    }
  }

  auto stage = [&](int buf, int k0) {
#pragma unroll
    for (int i = 0; i < 4; i++) {
      int slot = i * 256 + tid;
      int row = slot >> 3, j = slot & 7;
      int c8 = ((j ^ swz(row)) & 7) * 8;
      gload16(&A[(size_t)(bm * 128 + row) * CDIM + k0 + c8], &lds_a[buf][slot * 8]);
      gload16(&Bt[(size_t)(bn * 128 + row) * CDIM + k0 + c8], &lds_b[buf][slot * 8]);
    }
  };

  stage(0, 0);
  asm volatile("s_waitcnt vmcnt(0)" ::: "memory");
  __builtin_amdgcn_s_barrier();
  __builtin_amdgcn_sched_barrier(0);

  int cur = 0;
#pragma unroll 2
  for (int t = 0; t < 12; t++) {
    if (t < 11) stage(cur ^ 1, (t + 1) * 64);
#pragma unroll
    for (int kk = 0; kk < 2; kk++) {
      bf16x8 af[4], bfr[4];
#pragma unroll
      for (int mi = 0; mi < 4; mi++)
        af[mi] = *reinterpret_cast<const bf16x8*>(&lds_a[cur][aoff[kk][mi]]);
#pragma unroll
      for (int ni = 0; ni < 4; ni++)
        bfr[ni] = *reinterpret_cast<const bf16x8*>(&lds_b[cur][boff[kk][ni]]);
      __builtin_amdgcn_s_setprio(1);
#pragma unroll
      for (int mi = 0; mi < 4; mi++)
#pragma unroll
        for (int ni = 0; ni < 4; ni++)
          acc[mi][ni] = mfma16(af[mi], bfr[ni], acc[mi][ni]);
      __builtin_amdgcn_s_setprio(0);
    }
    asm volatile("s_waitcnt vmcnt(0) lgkmcnt(0)" ::: "memory");
    __builtin_amdgcn_s_barrier();
    __builtin_amdgcn_sched_barrier(0);
    cur ^= 1;
  }

#pragma unroll
  for (int mi = 0; mi < 4; mi++)
#pragma unroll
    for (int ni = 0; ni < 4; ni++)
#pragma unroll
      for (int r = 0; r < 4; r++) {
        int grow = bm * 128 + wr * 64 + mi * 16 + 4 * lg + r;
        int gcol = bn * 128 + wc * 64 + ni * 16 + l16;
        outp[(size_t)grow * CDIM + gcol] =
            acc[mi][ni][r] + b0[gcol] + extra[(size_t)grow * CDIM + gcol];
      }
}

// -------- Flash attention v10: pos added to Q in prologue --------------------
__global__ __launch_bounds__(256, 3) void attn_kernel(const ushort_t* __restrict__ QKV,
                                                      const float* __restrict__ pos,
                                                      ushort_t* __restrict__ O) {
  const int b = blockIdx.x, h = blockIdx.y, qt = blockIdx.z;

  const int tid = threadIdx.x, lane = tid & 63, w = tid >> 6;
  const int l16 = lane & 15, lg = lane >> 4;
  const int tb = b * 1024 + qt * 128;
  const int co_q = h * HD, co_k = CDIM + h * HD, co_v = 2 * CDIM + h * HD;

  __shared__ __align__(16) ushort_t k_lds[2][64 * 64];
  __shared__ __align__(16) ushort_t vt_lds[2][64 * 64];
  __shared__ __align__(16) ushort_t p_lds[128 * 64];

  // Q fragments: q' from gemm0 = (xWq+bq)*QSCALE; add pos*QSCALE here
  bf16x8 qf[2][2];
#pragma unroll
  for (int mi = 0; mi < 2; mi++)
#pragma unroll
    for (int ds = 0; ds < 2; ds++) {
      int row = tb + w * 32 + mi * 16 + l16;
      int col = co_q + ds * 32 + 8 * lg;
      bf16x8 q = *reinterpret_cast<const bf16x8*>(&QKV[(size_t)row * QKV_N + col]);
      const float* pr = pos + (size_t)row * CDIM + col;
      float p[8];
      *reinterpret_cast<float4*>(&p[0]) = *reinterpret_cast<const float4*>(pr);
      *reinterpret_cast<float4*>(&p[4]) = *reinterpret_cast<const float4*>(pr + 4);
#pragma unroll
      for (int j = 0; j < 8; j++)
        q[j] = (short)f2bf(bf2f((ushort_t)q[j]) + p[j] * QSCALE);
      qf[mi][ds] = q;
    }

  float m_sm[2] = {MREF, MREF};
  float l_sm[2] = {0.f, 0.f};
  float m_acc[2][4];
#pragma unroll
  for (int mi = 0; mi < 2; mi++)
#pragma unroll
    for (int r = 0; r < 4; r++) m_acc[mi][r] = MREF;
  f32x4 oacc[2][4] = {};

  int kfoff[2][4];
#pragma unroll
  for (int ds = 0; ds < 2; ds++)
#pragma unroll
    for (int ni = 0; ni < 4; ni++) {
      int rr = ni * 16 + l16;
      kfoff[ds][ni] = rr * 64 + (((ds * 4 + lg) ^ swz(rr)) & 7) * 8;
    }
  int poff[2][4], paoff[2][2];
#pragma unroll
  for (int mi = 0; mi < 2; mi++) {
    int myq = w * 32 + mi * 16 + l16;
    int sq = swz(myq);
#pragma unroll
    for (int ni = 0; ni < 4; ni++)
      poff[mi][ni] = myq * 64 + (lg & 1) * 4 + (((ni * 2 + (lg >> 1)) ^ sq) & 7) * 8;
#pragma unroll
    for (int ks = 0; ks < 2; ks++)
      paoff[mi][ks] = myq * 64 + (((ks * 4 + lg) ^ sq) & 7) * 8;
  }
  int vboff[2][4];
#pragma unroll
  for (int ks = 0; ks < 2; ks++)
#pragma unroll
    for (int ni = 0; ni < 4; ni++) {
      int d = ni * 16 + l16;
      vboff[ks][ni] = d * 64 + (((ks * 4 + lg) ^ swz(d)) & 7) * 8;
    }

  auto stage_k = [&](int buf, int kt) {
    const int kv0 = kt * 64;
#pragma unroll
    for (int i = 0; i < 2; i++) {
      int slot = i * 256 + tid;
      int r = slot >> 3, j = slot & 7;
      int c = ((j ^ swz(r)) & 7) * 8;
      gload16(&QKV[(size_t)(b * 1024 + kv0 + r) * QKV_N + co_k + c],
              &k_lds[buf][slot * 8]);
    }
  };

  const int kv0 = (tid >> 3) * 2, d0 = (tid & 7) * 8;
  const int sV = ((kv0 >> 3) ^ (d0 >> 3)) & 7;
  int voff[8];
#pragma unroll
  for (int u = 0; u < 8; u++)
    voff[u] = (d0 + u) * 64 + ((sV ^ u) & 7) * 8 + (kv0 & 7);
  const ushort_t* vsrc = QKV + (size_t)(b * 1024 + kv0) * QKV_N + co_v + d0;

  uint4 vr0, vr1;
  auto load_v = [&](int kt) {
    vr0 = *reinterpret_cast<const uint4*>(vsrc + (size_t)kt * 64 * QKV_N);
    vr1 = *reinterpret_cast<const uint4*>(vsrc + (size_t)kt * 64 * QKV_N + QKV_N);
  };
  auto write_v = [&](int buf) {
    const unsigned* w0 = reinterpret_cast<const unsigned*>(&vr0);
    const unsigned* w1 = reinterpret_cast<const unsigned*>(&vr1);
#pragma unroll
    for (int u = 0; u < 8; u++) {
      unsigned a = w0[u >> 1], c = w1[u >> 1];
      unsigned val = (u & 1) ? ((a >> 16) | (c & 0xffff0000u))
                             : ((a & 0xffffu) | (c << 16));
      *reinterpret_cast<unsigned*>(&vt_lds[buf][voff[u]]) = val;
    }
  };

  stage_k(0, 0);
  load_v(0);
  write_v(0);
  asm volatile("s_waitcnt vmcnt(0) lgkmcnt(0)" ::: "memory");
  __builtin_amdgcn_s_barrier();
  __builtin_amdgcn_sched_barrier(0);

  for (int kt = 0; kt < 16; kt++) {
    const int cur = kt & 1, nxt = cur ^ 1;
    if (kt < 15) { stage_k(nxt, kt + 1); load_v(kt + 1); }

    bf16x8 kf[2][4];
#pragma unroll
    for (int ds = 0; ds < 2; ds++)
#pragma unroll
      for (int ni = 0; ni < 4; ni++)
        kf[ds][ni] = *reinterpret_cast<const bf16x8*>(&k_lds[cur][kfoff[ds][ni]]);

#pragma unroll
    for (int mi = 0; mi < 2; mi++) {
      f32x4 st[4] = {};
      __builtin_amdgcn_s_setprio(1);
#pragma unroll
      for (int ds = 0; ds < 2; ds++)
#pragma unroll
        for (int ni = 0; ni < 4; ni++)
          st[ni] = mfma16(kf[ds][ni], qf[mi][ds], st[ni]);
      __builtin_amdgcn_s_setprio(0);

      float t0 = fmaxf(fmaxf(st[0][0], st[0][1]), fmaxf(st[0][2], st[0][3]));
      float t1 = fmaxf(fmaxf(st[1][0], st[1][1]), fmaxf(st[1][2], st[1][3]));
      float t2 = fmaxf(fmaxf(st[2][0], st[2][1]), fmaxf(st[2][2], st[2][3]));
      float t3 = fmaxf(fmaxf(st[3][0], st[3][1]), fmaxf(st[3][2], st[3][3]));
      float tm = fmaxf(fmaxf(t0, t1), fmaxf(t2, t3));

      if (__any(tm > m_sm[mi])) {
        float rm = fmaxf(tm, __shfl_xor(tm, 16));
        rm = fmaxf(rm, __shfl_xor(rm, 32));
        float mnew = fmaxf(m_sm[mi], rm);
        l_sm[mi] *= exp2f(m_sm[mi] - mnew);
        m_sm[mi] = mnew;
#pragma unroll
        for (int r = 0; r < 4; r++) {
          float mn = __shfl(mnew, 4 * lg + r);
          float corr = exp2f(m_acc[mi][r] - mn);
          m_acc[mi][r] = mn;
#pragma unroll
          for (int ni = 0; ni < 4; ni++) oacc[mi][ni][r] *= corr;
        }
      }

      float ps[4];
#pragma unroll
      for (int ni = 0; ni < 4; ni++) {
        float e0 = exp2f(st[ni][0] - m_sm[mi]);
        float e1 = exp2f(st[ni][1] - m_sm[mi]);
        float e2 = exp2f(st[ni][2] - m_sm[mi]);
        float e3 = exp2f(st[ni][3] - m_sm[mi]);
        st[ni][0] = e0; st[ni][1] = e1; st[ni][2] = e2; st[ni][3] = e3;
        ps[ni] = (e0 + e1) + (e2 + e3);
      }
      l_sm[mi] += (ps[0] + ps[1]) + (ps[2] + ps[3]);

#pragma unroll
      for (int ni = 0; ni < 4; ni++) {
        unsigned p01, p23;
        asm("v_cvt_pk_bf16_f32 %0, %1, %2" : "=v"(p01) : "v"(st[ni][0]), "v"(st[ni][1]));
        asm("v_cvt_pk_bf16_f32 %0, %1, %2" : "=v"(p23) : "v"(st[ni][2]), "v"(st[ni][3]));
        uint2 pk; pk.x = p01; pk.y = p23;
        *reinterpret_cast<uint2*>(&p_lds[poff[mi][ni]]) = pk;
      }
    }

#pragma unroll
    for (int ks = 0; ks < 2; ks++) {
      bf16x8 pa0 = *reinterpret_cast<const bf16x8*>(&p_lds[paoff[0][ks]]);
      bf16x8 pa1 = *reinterpret_cast<const bf16x8*>(&p_lds[paoff[1][ks]]);
      bf16x8 vb[4];
#pragma unroll
      for (int ni = 0; ni < 4; ni++)
        vb[ni] = *reinterpret_cast<const bf16x8*>(&vt_lds[cur][vboff[ks][ni]]);
      __builtin_amdgcn_s_setprio(1);
#pragma unroll
      for (int ni = 0; ni < 4; ni++) {
        oacc[0][ni] = mfma16(pa0, vb[ni], oacc[0][ni]);
        oacc[1][ni] = mfma16(pa1, vb[ni], oacc[1][ni]);
      }
      __builtin_amdgcn_s_setprio(0);
    }

    if (kt < 15) write_v(nxt);
    asm volatile("s_waitcnt vmcnt(0) lgkmcnt(0)" ::: "memory");
    __builtin_amdgcn_s_barrier();
    __builtin_amdgcn_sched_barrier(0);
  }

#pragma unroll
  for (int mi = 0; mi < 2; mi++) {
    float l = l_sm[mi];
    l += __shfl_xor(l, 16);
    l += __shfl_xor(l, 32);
#pragma unroll
    for (int r = 0; r < 4; r++) {
      float lr = __shfl(l, 4 * lg + r);
      float inv = 1.f / lr;
      int grow = tb + w * 32 + mi * 16 + 4 * lg + r;
#pragma unroll
      for (int ni = 0; ni < 4; ni++) {
        int gcol = h * HD + ni * 16 + l16;
        O[(size_t)grow * CDIM + gcol] = f2bf(oacc[mi][ni][r] * inv);
      }
    }
  }
}

extern "C" void kernel_launch(void* const* d_in, const int* in_sizes, int n_in,
                              void* d_out, int out_size, void* d_ws, size_t ws_size,
                              hipStream_t stream) {
  const float* x     = (const float*)d_in[0];
  const float* pos   = (const float*)d_in[1];
  const float* gamma = (const float*)d_in[2];
  const float* beta  = (const float*)d_in[3];
  const float* Wq    = (const float*)d_in[4];
  const float* bq    = (const float*)d_in[5];
  const float* Wk    = (const float*)d_in[6];
  const float* bk    = (const float*)d_in[7];
  const float* Wv    = (const float*)d_in[8];
  const float* bv    = (const float*)d_in[9];
  const float* Wo    = (const float*)d_in[10];
  const float* bo    = (const float*)d_in[11];
  float* out = (float*)d_out;

  ushort_t* xn   = (ushort_t*)d_ws;                    // 8192*768
  ushort_t* wt   = xn + (size_t)TOK * CDIM;            // 3072*768 (q,k,v,o transposed)
  ushort_t* qkv  = wt + (size_t)3072 * CDIM;           // 8192*2304
  ushort_t* aout = qkv + (size_t)TOK * QKV_N;          // 8192*768

  prep_kernel<<<TOK + 2304, 256, 0, stream>>>(x, gamma, beta, xn,
                                              Wq, Wk, Wv, Wo, wt);
  gemm0_kernel<<<1152, 256, 0, stream>>>(xn, wt, bq, bk, bv, qkv);
  attn_kernel<<<dim3(8, NH, 8), 256, 0, stream>>>(qkv, pos, aout);
  gemm1_kernel<<<dim3(6, 64), 256, 0, stream>>>(aout, wt + (size_t)QKV_N * CDIM,
                                                bo, x, out);
}